// Round 1
// 1838.489 us; speedup vs baseline: 1.1840x; 1.1840x over previous
//
#include <hip/hip_runtime.h>
#include <cstdint>
#include <cstddef>

// LaminarV1V2Network: B=1024, T=512, N=36, H=128, D_in=74, K=202.
// R5: (a) A-tile bank-conflict fix: KP 224->240 (row stride 24 words mod 32 ->
//     uniform bank groups), hb stride 128->144; (b) P6 softmax via 16-lane DPP
//     butterfly (quad_perm/mirrors) instead of 13 serial ds_bpermute; (c) ring
//     dots unified into one branch-free body with hoisted pointers; (d)
//     v_cvt_pk_bf16_f32 for all hi/lo bf16 packing; (e) 2-chain MFMA accum in P3.
// 256 blocks x 512 threads, 4 rows/block, 4 lgkm-only barriers/step.

#define NN   36
#define HH   128
#define DIN  74
#define KT   202
#define KP   240      // padded K slabs; 480B row = 120 words = 24 mod 32 -> bank-uniform
#define TT   512
#define RPB  4
#define NPAD 40
#define WSTR 44       // LDS ring-weight row stride (floats)
#define HSTR 144      // hb row stride (shorts): 72 words = 8 mod 32 -> bank-uniform

typedef short bf16x8 __attribute__((ext_vector_type(8)));
typedef float f32x4  __attribute__((ext_vector_type(4)));

#define MFMA(a,b,c) __builtin_amdgcn_mfma_f32_16x16x32_bf16((a),(b),(c),0,0,0)
// Barrier that orders LDS only: global loads/stores float across it.
#define BAR() asm volatile("s_waitcnt lgkmcnt(0)\n\ts_barrier" ::: "memory")

__device__ __forceinline__ float fastrcp(float x) { return __builtin_amdgcn_rcpf(x); }
__device__ __forceinline__ float sigmf(float x) { return fastrcp(1.0f + __expf(-x)); }
__device__ __forceinline__ float tanhf_fast(float x) {
    return 1.0f - 2.0f * fastrcp(1.0f + __expf(2.0f * x));
}

__device__ __forceinline__ short f2bf(float v) {
    union { float f; unsigned u; } x; x.f = v;
    unsigned r = (x.u + 0x7fffu + ((x.u >> 16) & 1u)) >> 16;   // RNE
    return (short)r;
}
__device__ __forceinline__ float bf2f(short s) {
    union { unsigned u; float f; } y; y.u = ((unsigned)(unsigned short)s) << 16;
    return y.f;
}

// v_cvt_pk_bf16_f32: dst[15:0]=bf16(a), dst[31:16]=bf16(b), RNE (same as f2bf).
__device__ __forceinline__ unsigned cvtpk(float a, float b) {
    unsigned r;
    asm("v_cvt_pk_bf16_f32 %0, %1, %2" : "=v"(r) : "v"(a), "v"(b));
    return r;
}
__device__ __forceinline__ float lo16f(unsigned p) { return __uint_as_float(p << 16); }
__device__ __forceinline__ float hi16f(unsigned p) { return __uint_as_float(p & 0xffff0000u); }

// 16-lane butterfly reduction at VALU speed via DPP (quad_perm xor1/xor2,
// row_half_mirror pairs 4-groups, row_mirror pairs 8-groups).
#define DPP_STEP_MAX(x, ctrl) \
    x = fmaxf(x, __int_as_float(__builtin_amdgcn_update_dpp(0, __float_as_int(x), (ctrl), 0xF, 0xF, true)))
#define DPP_STEP_SUM(x, ctrl) \
    x = x + __int_as_float(__builtin_amdgcn_update_dpp(0, __float_as_int(x), (ctrl), 0xF, 0xF, true))

__device__ __forceinline__ float red16_max(float x) {
    DPP_STEP_MAX(x, 0xB1);   // quad_perm(1,0,3,2)  = xor1
    DPP_STEP_MAX(x, 0x4E);   // quad_perm(2,3,0,1)  = xor2
    DPP_STEP_MAX(x, 0x141);  // row_half_mirror
    DPP_STEP_MAX(x, 0x140);  // row_mirror
    return x;
}
__device__ __forceinline__ float red16_sum(float x) {
    DPP_STEP_SUM(x, 0xB1);
    DPP_STEP_SUM(x, 0x4E);
    DPP_STEP_SUM(x, 0x141);
    DPP_STEP_SUM(x, 0x140);
    return x;
}

// ---- fragment layout in ws (shorts) ----
// GRU tiles T = m*8+nt (m: 0=Wz,1=Wr,2=Wh; nt: 16-feature tile), 7 slabs:
//   off = T*7*512 + s*512 + lane*8 + j ;  k = s*32 + (lane>>4)*8 + j, n = nt*16 + (lane&15)
// HEAD tiles t in [0,3), 4 slabs, base 86016:
//   off = 86016 + (t*4+s)*512 + lane*8 + j ; cols: <36 Wq, ==36 Wp, else 0
#define HEADBASE 86016
#define FRAG_TOTAL 92160

extern "C" __global__ void __launch_bounds__(256)
init_frags(const float* __restrict__ Wz, const float* __restrict__ Wr,
           const float* __restrict__ Wh, const float* __restrict__ Wq,
           const float* __restrict__ Wp, short* __restrict__ frag)
{
    int idx = blockIdx.x * 256 + threadIdx.x;
    if (idx >= FRAG_TOTAL) return;
    float v;
    if (idx < HEADBASE) {
        int T = idx / 3584; int rem = idx - T * 3584;
        int s = rem >> 9;   int e = rem & 511;
        int l = e >> 3, j = e & 7;
        int k = s * 32 + ((l >> 4) << 3) + j;
        int n = ((T & 7) << 4) + (l & 15);
        const float* W = (T < 8) ? Wz : (T < 16) ? Wr : Wh;
        v = (k < KT) ? W[k * HH + n] : 0.f;
    } else {
        int r2 = idx - HEADBASE;
        int ts = r2 >> 9; int e = r2 & 511;
        int t = ts >> 2, s = ts & 3;
        int l = e >> 3, j = e & 7;
        int k = s * 32 + ((l >> 4) << 3) + j;     // < 128
        int c = (t << 4) + (l & 15);
        v = (c < NN) ? Wq[k * NN + c] : (c == NN ? Wp[k] : 0.f);
    }
    frag[idx] = f2bf(v);
}

extern "C" __global__ void __launch_bounds__(512, 2)
laminar_kernel(const float* __restrict__ packed,
               const float* __restrict__ Wl4,
               const float* __restrict__ Wl23,
               const float* __restrict__ Wsom,
               const float* __restrict__ bz,
               const float* __restrict__ br,
               const float* __restrict__ bh,
               const float* __restrict__ bq,
               const float* __restrict__ bp,
               const short* __restrict__ frag,
               float* __restrict__ out)
{
    const int tid  = threadIdx.x;
    const int r0   = blockIdx.x * RPB;
    const int lane = tid & 63;
    const int w    = tid >> 6;
    const int m    = lane & 15;
    const int q    = lane >> 4;
    const int ma   = m & 3;              // batch row within A tile
    const int sel  = (m >> 2) & 1;       // 0: hi operand rows, 1: lo operand rows

    __shared__ __align__(16) short xa_hi[RPB][KP], xa_lo[RPB][KP];  // z/r A: [x, h]
    __shared__ __align__(16) short xb_hi[RPB][KP], xb_lo[RPB][KP];  // hh  A: [x, r*h]
    __shared__ __align__(16) short hb_hi[RPB][HSTR], hb_lo[RPB][HSTR]; // head A: h_new
    __shared__ float hS[HH][5];      // h state, [feature][row], stride-5
    __shared__ float zgS[HH][5];     // z gate
    __shared__ float preq[48][5];    // head pre-acts, [col][row]
    __shared__ __align__(16) float Wl4S[NN * WSTR], Wl23S[NN * WSTR], WsomS[NN * WSTR];
    __shared__ __align__(16) float l4s[RPB][NPAD], l23s[RPB][NPAD];
    __shared__ __align__(16) float soms[RPB][NPAD], adL[RPB][NPAD];
    __shared__ __align__(16) float l4part[RPB][NPAD];   // stim(t)+Wl4*l4(t-1)-adapt(t-1)
    __shared__ __align__(16) float l23dotS[RPB][NPAD];  // Wl23*l23(t-1)
    __shared__ __align__(16) float somdotS[RPB][NPAD];  // Wsom*som(t-1)
    __shared__ float bzL[HH], brL[HH], bhL[HH], bqL[48];
    __shared__ float pvL[RPB];
    __shared__ float bpS;

    // ---- one-time init ----
    for (int i = tid; i < HH; i += 512) { bzL[i] = bz[i]; brL[i] = br[i]; bhL[i] = bh[i]; }
    for (int i = tid; i < 48; i += 512) bqL[i] = (i < NN) ? bq[i] : 0.f;
    if (tid == 0) bpS = bp[0];
    for (int idx = tid; idx < NN * NN; idx += 512) {
        const int i = idx / NN, j = idx - i * NN;
        Wl4S[i * WSTR + j]  = Wl4[idx];
        Wl23S[i * WSTR + j] = Wl23[idx];
        WsomS[i * WSTR + j] = Wsom[idx];
    }
    { short* p = (short*)xa_hi; for (int i = tid; i < RPB*KP; i += 512) p[i] = 0; }
    { short* p = (short*)xa_lo; for (int i = tid; i < RPB*KP; i += 512) p[i] = 0; }
    { short* p = (short*)xb_hi; for (int i = tid; i < RPB*KP; i += 512) p[i] = 0; }
    { short* p = (short*)xb_lo; for (int i = tid; i < RPB*KP; i += 512) p[i] = 0; }
    { float* p = (float*)hS;    for (int i = tid; i < HH*5;    i += 512) p[i] = 0.f; }
    { float* p = (float*)l4s;   for (int i = tid; i < RPB*NPAD; i += 512) {
        p[i] = 0.f; ((float*)l23s)[i] = 0.f; ((float*)soms)[i] = 0.f;
        ((float*)adL)[i] = 0.f; ((float*)l23dotS)[i] = 0.f; ((float*)somdotS)[i] = 0.f; } }
    if (tid < RPB) pvL[tid] = 0.f;
    // l4part(0) = stim(0) (all state zero)
    if (tid < 144) {
        const int r = tid / NN, i = tid - (tid / NN) * NN;
        l4part[r][i] = packed[((size_t)(r0 + r) * TT + 0) * DIN + i];
    }

    // ---- persistent weight fragments in VGPRs ----
    const int g   = w >> 2;      // P1 gate (0=z waves 0-3, 1=r waves 4-7)
    const int nt0 = w & 3;       // P1 tiles nt0, nt0+4
    bf16x8 Wg0[7], Wg1[7], WhR[7], WhdR[4];
    {
        const short* b0 = frag + ((g * 8 + nt0) * 7) * 512 + lane * 8;
        const short* b1 = frag + ((g * 8 + nt0 + 4) * 7) * 512 + lane * 8;
        #pragma unroll
        for (int s = 0; s < 7; ++s) {
            Wg0[s] = *(const bf16x8*)(b0 + s * 512);
            Wg1[s] = *(const bf16x8*)(b1 + s * 512);
        }
        const short* b2 = frag + ((16 + w) * 7) * 512 + lane * 8;
        #pragma unroll
        for (int s = 0; s < 7; ++s) WhR[s] = *(const bf16x8*)(b2 + s * 512);
        const int hw = (w < 3) ? w : 0;
        const short* b3 = frag + HEADBASE + (hw * 4) * 512 + lane * 8;
        #pragma unroll
        for (int s = 0; s < 4; ++s) WhdR[s] = *(const bf16x8*)(b3 + s * 512);
    }

    // ---- loop-invariant pointers for the unified ring dots (P1, tid 144..431) ----
    const int du   = (tid >= 144 && tid < 432) ? (tid - 144) : 0;
    const int dsel = (du >= 144);                      // 0: l23dot, 1: somdot
    const int dv   = du - (dsel ? 144 : 0);
    const int drr  = dv / 36, dii = dv - drr * 36;
    const float* dW    = (dsel ? WsomS : Wl23S) + dii * WSTR;
    const float* dSrow = (dsel ? &soms[0][0] : &l23s[0][0]) + drr * NPAD;
    float*       dD    = (dsel ? &somdotS[0][0] : &l23dotS[0][0]) + drr * NPAD + dii;

    // ---- cue/task prologue: stage t=0, prefetch t=1 (2 cols/thread) ----
    float ctv0 = 0.f, ctv1 = 0.f; int ctr = 0, ctc = 0;
    if (tid >= 400 && tid < 476) {
        const int u = tid - 400; ctr = u / 19; ctc = 36 + 2 * (u - ctr * 19);
        const size_t base0 = ((size_t)(r0 + ctr) * TT + 0) * DIN;
        #pragma unroll
        for (int d = 0; d < 2; ++d) {
            const float v = packed[base0 + ctc + d];
            const short hi = f2bf(v), lo = f2bf(v - bf2f(hi));
            xa_hi[ctr][ctc + d] = hi; xa_lo[ctr][ctc + d] = lo;
            if (ctc + d >= 64) { xb_hi[ctr][ctc + d] = hi; xb_lo[ctr][ctc + d] = lo; }
        }
        const size_t base1 = ((size_t)(r0 + ctr) * TT + 1) * DIN;
        ctv0 = packed[base1 + ctc]; ctv1 = packed[base1 + ctc + 1];
    }
    // stim prefetch regs (used by P5's l4part) + loop-invariant l4part pointers
    float stimreg = 0.f; int sr = 0, si = 0;
    if (tid >= 256 && tid < 400) { const int u = tid - 256; sr = u / NN; si = u - sr * NN; }
    const float* pW4 = Wl4S + si * WSTR;
    const float* pS4 = &l4s[0][0] + sr * NPAD;
    float*       pD4 = &l4part[0][0] + sr * NPAD + si;
    __syncthreads();

    for (int t = 0; t < TT; ++t) {
        // ---- P1: z,r MFMA (hi/lo packed rows) + gate epilogue
        //          + l4 finalize + unified l23/som dot + stim prefetch ----
        bf16x8 Apk[7];
        {
            const short* xaP = sel ? &xa_lo[ma][0] : &xa_hi[ma][0];
            #pragma unroll
            for (int s = 0; s < 7; ++s)
                Apk[s] = *(const bf16x8*)&xaP[s * 32 + q * 8];
            f32x4 a0 = {0.f,0.f,0.f,0.f}, a1 = {0.f,0.f,0.f,0.f};
            #pragma unroll
            for (int s = 0; s < 7; ++s) {
                a0 = MFMA(Apk[s], Wg0[s], a0);
                a1 = MFMA(Apk[s], Wg1[s], a1);
            }
            #pragma unroll
            for (int e = 0; e < 4; ++e) {       // hi rows (0-3) + lo rows (4-7)
                a0[e] += __shfl_xor(a0[e], 16);
                a1[e] += __shfl_xor(a1[e], 16);
            }
            if (lane < 16) {
                const int fA = nt0 * 16 + lane;
                const int fB = fA + 64;
                if (g == 0) {
                    #pragma unroll
                    for (int e = 0; e < 4; ++e) {
                        zgS[fA][e] = sigmf(a0[e] + bzL[fA]);
                        zgS[fB][e] = sigmf(a1[e] + bzL[fB]);
                    }
                } else {
                    #pragma unroll
                    for (int e = 0; e < 4; ++e) {
                        const float ra = sigmf(a0[e] + brL[fA]) * hS[fA][e];
                        const float rb = sigmf(a1[e] + brL[fB]) * hS[fB][e];
                        const unsigned ph = cvtpk(ra, rb);
                        const unsigned pl = cvtpk(ra - lo16f(ph), rb - hi16f(ph));
                        xb_hi[e][DIN + fA] = (short)ph;
                        xb_lo[e][DIN + fA] = (short)pl;
                        xb_hi[e][DIN + fB] = (short)(ph >> 16);
                        xb_lo[e][DIN + fB] = (short)(pl >> 16);
                    }
                }
            }
        }
        if (tid < 144) {                       // l4(t) finalize from l4part(t), pv(t-1)
            const int r = tid / NN, i = tid - (tid / NN) * NN;
            const float nl4 = 0.9f * l4s[r][i] + 0.1f * fmaxf(l4part[r][i] - pvL[r], 0.f);
            l4s[r][i] = nl4;
            adL[r][i] = 0.98f * adL[r][i] + 0.01f * nl4;
        } else if (tid < 432) {                // unified l23dot/somdot (branch-free body)
            float acc = 0.f;
            #pragma unroll
            for (int j = 0; j < NN; j += 4) {
                const float4 sv = *(const float4*)&dSrow[j];
                const float4 wv = *(const float4*)&dW[j];
                acc += sv.x*wv.x + sv.y*wv.y + sv.z*wv.z + sv.w*wv.w;
            }
            *dD = acc;
        }
        if (tid >= 256 && tid < 400) {         // stim(t+1) for P5's l4part(t+1)
            const int tn = (t + 1 < TT) ? t + 1 : t;
            stimreg = packed[((size_t)(r0 + sr) * TT + tn) * DIN + si];
        }
        BAR();

        // ---- P3: hh MFMA (2 accumulator chains) + fused h update ----
        {
            const short* xbP = sel ? &xb_lo[ma][0] : &xb_hi[ma][0];
            bf16x8 Bpk[5];
            #pragma unroll
            for (int s = 0; s < 5; ++s)
                Bpk[s] = *(const bf16x8*)&xbP[(s + 2) * 32 + q * 8];
            f32x4 a = {0.f,0.f,0.f,0.f}, b = {0.f,0.f,0.f,0.f};
            a = MFMA(Apk[0], WhR[0], a);
            b = MFMA(Apk[1], WhR[1], b);
            a = MFMA(Bpk[0], WhR[2], a);
            b = MFMA(Bpk[1], WhR[3], b);
            a = MFMA(Bpk[2], WhR[4], a);
            b = MFMA(Bpk[3], WhR[5], b);
            a = MFMA(Bpk[4], WhR[6], a);
            a = a + b;
            #pragma unroll
            for (int e = 0; e < 4; ++e) a[e] += __shfl_xor(a[e], 16);
            if (lane < 16) {
                const int f = (w << 4) + lane;     // 0..127
                float hn[4];
                #pragma unroll
                for (int e = 0; e < 4; ++e) {
                    const float hhv = tanhf_fast(a[e] + bhL[f]);
                    const float zg  = zgS[f][e];
                    hn[e] = (1.0f - zg) * hS[f][e] + zg * hhv;
                    hS[f][e] = hn[e];
                }
                #pragma unroll
                for (int p = 0; p < 2; ++p) {
                    const float x0 = hn[2*p], x1 = hn[2*p + 1];
                    const unsigned ph = cvtpk(x0, x1);
                    const unsigned pl = cvtpk(x0 - lo16f(ph), x1 - hi16f(ph));
                    const short s00 = (short)ph, s01 = (short)(ph >> 16);
                    const short s10 = (short)pl, s11 = (short)(pl >> 16);
                    hb_hi[2*p][f]     = s00; hb_lo[2*p][f]     = s10;
                    hb_hi[2*p+1][f]   = s01; hb_lo[2*p+1][f]   = s11;
                    xa_hi[2*p][DIN+f]   = s00; xa_lo[2*p][DIN+f]   = s10;
                    xa_hi[2*p+1][DIN+f] = s01; xa_lo[2*p+1][DIN+f] = s11;
                }
            }
        }
        BAR();

        // ---- P5: heads MFMA (w<3) | PV (w==3) | l4part(t+1) | cue/task(t+1) ----
        if (w < 3) {
            const short* hbP = sel ? &hb_lo[ma][0] : &hb_hi[ma][0];
            bf16x8 Hk[4];
            #pragma unroll
            for (int s = 0; s < 4; ++s)
                Hk[s] = *(const bf16x8*)&hbP[s * 32 + q * 8];
            f32x4 a = {0.f,0.f,0.f,0.f};
            #pragma unroll
            for (int s = 0; s < 4; ++s) a = MFMA(Hk[s], WhdR[s], a);
            #pragma unroll
            for (int e = 0; e < 4; ++e) a[e] += __shfl_xor(a[e], 16);
            if (lane < 16) {
                #pragma unroll
                for (int e = 0; e < 4; ++e) preq[w * 16 + lane][e] = a[e];
            }
        } else if (w == 3) {                   // PV: l4(t) + l23(t-1), DPP reduce
            const int row = lane >> 4;
            const int jj  = lane & 15;
            float s = 0.f;
            for (int j = jj; j < NN; j += 16) s += l4s[row][j] + l23s[row][j];
            s = red16_sum(s);
            if (jj == 0) pvL[row] = 0.9f * pvL[row] + 0.1f * fmaxf(s * (1.0f / 36.0f), 0.f);
        }
        if (tid >= 256 && tid < 400) {         // l4part(t+1) = stim(t+1)+Wl4*l4(t)-adapt(t)
            float acc = stimreg - adL[sr][si];
            #pragma unroll
            for (int j = 0; j < NN; j += 4) {
                const float4 sv = *(const float4*)&pS4[j];
                const float4 wv = *(const float4*)&pW4[j];
                acc += sv.x*wv.x + sv.y*wv.y + sv.z*wv.z + sv.w*wv.w;
            }
            *pD4 = acc;
        } else if (tid >= 400 && tid < 476) {  // cue/task(t+1) -> LDS; prefetch t+2
            const unsigned ph = cvtpk(ctv0, ctv1);
            const unsigned pl = cvtpk(ctv0 - lo16f(ph), ctv1 - hi16f(ph));
            xa_hi[ctr][ctc]     = (short)ph;        xa_lo[ctr][ctc]     = (short)pl;
            xa_hi[ctr][ctc + 1] = (short)(ph >> 16); xa_lo[ctr][ctc + 1] = (short)(pl >> 16);
            if (ctc >= 64) {   // ctc is even, so ctc>=64 <=> ctc+1>=64
                xb_hi[ctr][ctc]     = (short)ph;        xb_lo[ctr][ctc]     = (short)pl;
                xb_hi[ctr][ctc + 1] = (short)(ph >> 16); xb_lo[ctr][ctc + 1] = (short)(pl >> 16);
            }
            const int tn = (t + 2 < TT) ? t + 2 : TT - 1;
            const size_t base = ((size_t)(r0 + ctr) * TT + tn) * DIN;
            ctv0 = packed[base + ctc]; ctv1 = packed[base + ctc + 1];
        }
        BAR();

        // ---- P6: softmax+pi (DPP butterfly, lanes 0-15 x 3 col slots)
        //          + pointwise SOM/L23 updates + output, wave=row ----
        if (tid < 256) {
            const int rr = w;   // 0..3
            const float v0 = preq[m][rr] + bqL[m];
            const float v1 = preq[m + 16][rr] + bqL[m + 16];
            const float v2 = (m < 4) ? (preq[m + 32][rr] + bqL[m + 32]) : -1e30f;
            const float pi = sigmf(preq[36][rr] + bpS);
            const float mx = red16_max(fmaxf(fmaxf(v0, v1), v2));
            const float e0 = __expf(v0 - mx);
            const float e1 = __expf(v1 - mx);
            const float e2 = (m < 4) ? __expf(v2 - mx) : 0.f;
            const float ss = red16_sum(e0 + e1 + e2);
            const float sc = fastrcp(ss) * pi;
            if (lane < 16) {
                const float pv = pvL[rr];
                const size_t outb = ((size_t)(r0 + rr) * TT + t) * NN;
                float ln01[2];
                #pragma unroll
                for (int t2 = 0; t2 < 2; ++t2) {
                    const int i = m + 16 * t2;
                    const float dt = (t2 ? e1 : e0) * sc;
                    const float sn = 0.9f * soms[rr][i]
                                   + 0.1f * fmaxf(dt + somdotS[rr][i], 0.f);
                    soms[rr][i] = sn;
                    const float acc2 = (l4s[rr][i] - dt) * (1.0f + 0.5f * dt)
                                     + l23dotS[rr][i] - 0.8f * sn - pv;
                    const float ln = 0.9f * l23s[rr][i] + 0.1f * fmaxf(acc2, 0.f);
                    l23s[rr][i] = ln;
                    out[outb + i] = ln;
                    ln01[t2] = ln;
                }
                const unsigned ph = cvtpk(ln01[0], ln01[1]);
                const unsigned pl = cvtpk(ln01[0] - lo16f(ph), ln01[1] - hi16f(ph));
                xa_hi[rr][m]      = (short)ph;        xa_lo[rr][m]      = (short)pl;
                xa_hi[rr][m + 16] = (short)(ph >> 16); xa_lo[rr][m + 16] = (short)(pl >> 16);
                if (m < 4) {
                    const int i = m + 32;
                    const float dt = e2 * sc;
                    const float sn = 0.9f * soms[rr][i]
                                   + 0.1f * fmaxf(dt + somdotS[rr][i], 0.f);
                    soms[rr][i] = sn;
                    const float acc2 = (l4s[rr][i] - dt) * (1.0f + 0.5f * dt)
                                     + l23dotS[rr][i] - 0.8f * sn - pv;
                    const float ln = 0.9f * l23s[rr][i] + 0.1f * fmaxf(acc2, 0.f);
                    l23s[rr][i] = ln;
                    out[outb + i] = ln;
                    const short hi2 = f2bf(ln);
                    xa_hi[rr][i] = hi2; xa_lo[rr][i] = f2bf(ln - bf2f(hi2));
                }
            }
        }
        BAR();
    }
}

extern "C" void kernel_launch(void* const* d_in, const int* in_sizes, int n_in,
                              void* d_out, int out_size, void* d_ws, size_t ws_size,
                              hipStream_t stream) {
    (void)in_sizes; (void)n_in; (void)out_size; (void)ws_size;
    const float* packed = (const float*)d_in[0];
    const float* Wl4    = (const float*)d_in[1];
    const float* Wl23   = (const float*)d_in[2];
    const float* Wsom   = (const float*)d_in[3];
    const float* Wz     = (const float*)d_in[4];
    const float* Wr     = (const float*)d_in[5];
    const float* Wh     = (const float*)d_in[6];
    const float* bz     = (const float*)d_in[7];
    const float* br     = (const float*)d_in[8];
    const float* bh     = (const float*)d_in[9];
    const float* Wq     = (const float*)d_in[10];
    const float* bq     = (const float*)d_in[11];
    const float* Wp     = (const float*)d_in[12];
    const float* bp     = (const float*)d_in[13];
    float* out  = (float*)d_out;
    short* frag = (short*)d_ws;   // needs 184320 B

    init_frags<<<(FRAG_TOTAL + 255) / 256, 256, 0, stream>>>(Wz, Wr, Wh, Wq, Wp, frag);
    laminar_kernel<<<256, 512, 0, stream>>>(packed, Wl4, Wl23, Wsom,
                                            bz, br, bh, bq, bp, frag, out);
}

// Round 3
// 1519.567 us; speedup vs baseline: 1.4325x; 1.2099x over previous
//
#include <hip/hip_runtime.h>
#include <cstdint>
#include <cstddef>

// LaminarV1V2Network: B=1024, T=512, N=36, H=128, D_in=74, K=202.
// R7: 256 blocks x 1024 threads (16 waves), RPB=4. Weight fragments SPLIT
// across wave groups: w0-7 hold {Wz,Wr} tile w (14 frags), w8-15 hold
// {Wh tile, head tile} (11 frags) -> ~122 regs/wave -> 4 waves/SIMD
// (launch_bounds(1024,4)). Role-split phases: P1 = z/r gemm (w0-7) ||
// l23dot (w8-10) || l4-finalize+stim (w13-15); P3 = h gemm (w8-15) ||
// somdot (w0-2) || PV (w6); P5 = heads (w8-10) || l4part-dot (w3-5) ||
// cue (w6-7); P6 = softmax+pointwise (w0-3). In-lane hi/lo combine via
// 8-row A packing (row = batch*2+part): NO shfl_xor. KP=232 / HSTR=136
// give bank-uniform 8-row maps. 4 lgkm-only barriers/step.

#define NN   36
#define HH   128
#define DIN  74
#define KT   202
#define KP   232      // row = 116 words == 20 mod 32 -> 8-row map bank-uniform
#define TT   512
#define RPB  4
#define NPAD 40
#define WSTR 44       // LDS ring-weight row stride (floats)
#define HSTR 136      // hb row stride (shorts): 68 words == 4 mod 32 -> bank-uniform
#define S2   6        // second-dim stride for hS/zgS/preq

typedef short bf16x8 __attribute__((ext_vector_type(8)));
typedef float f32x4  __attribute__((ext_vector_type(4)));

#define MFMA(a,b,c) __builtin_amdgcn_mfma_f32_16x16x32_bf16((a),(b),(c),0,0,0)
// Barrier that orders LDS only: global loads/stores float across it.
#define BAR() asm volatile("s_waitcnt lgkmcnt(0)\n\ts_barrier" ::: "memory")

__device__ __forceinline__ float fastrcp(float x) { return __builtin_amdgcn_rcpf(x); }
__device__ __forceinline__ float sigmf(float x) { return fastrcp(1.0f + __expf(-x)); }
__device__ __forceinline__ float tanhf_fast(float x) {
    return 1.0f - 2.0f * fastrcp(1.0f + __expf(2.0f * x));
}

__device__ __forceinline__ short f2bf(float v) {
    union { float f; unsigned u; } x; x.f = v;
    unsigned r = (x.u + 0x7fffu + ((x.u >> 16) & 1u)) >> 16;   // RNE
    return (short)r;
}
__device__ __forceinline__ float bf2f(short s) {
    union { unsigned u; float f; } y; y.u = ((unsigned)(unsigned short)s) << 16;
    return y.f;
}

// v_cvt_pk_bf16_f32: dst[15:0]=bf16(a), dst[31:16]=bf16(b), RNE (same as f2bf).
__device__ __forceinline__ unsigned cvtpk(float a, float b) {
    unsigned r;
    asm("v_cvt_pk_bf16_f32 %0, %1, %2" : "=v"(r) : "v"(a), "v"(b));
    return r;
}
__device__ __forceinline__ float lo16f(unsigned p) { return __uint_as_float(p << 16); }
__device__ __forceinline__ float hi16f(unsigned p) { return __uint_as_float(p & 0xffff0000u); }

// 16-lane butterfly reduction at VALU speed via DPP.
#define DPP_STEP_MAX(x, ctrl) \
    x = fmaxf(x, __int_as_float(__builtin_amdgcn_update_dpp(0, __float_as_int(x), (ctrl), 0xF, 0xF, true)))
#define DPP_STEP_SUM(x, ctrl) \
    x = x + __int_as_float(__builtin_amdgcn_update_dpp(0, __float_as_int(x), (ctrl), 0xF, 0xF, true))

__device__ __forceinline__ float red16_max(float x) {
    DPP_STEP_MAX(x, 0xB1);   // quad_perm xor1
    DPP_STEP_MAX(x, 0x4E);   // quad_perm xor2
    DPP_STEP_MAX(x, 0x141);  // row_half_mirror
    DPP_STEP_MAX(x, 0x140);  // row_mirror
    return x;
}
__device__ __forceinline__ float red16_sum(float x) {
    DPP_STEP_SUM(x, 0xB1);
    DPP_STEP_SUM(x, 0x4E);
    DPP_STEP_SUM(x, 0x141);
    DPP_STEP_SUM(x, 0x140);
    return x;
}

// ---- fragment layout in ws (shorts) ---- (unchanged from R5)
#define HEADBASE 86016
#define FRAG_TOTAL 92160

extern "C" __global__ void __launch_bounds__(256)
init_frags(const float* __restrict__ Wz, const float* __restrict__ Wr,
           const float* __restrict__ Wh, const float* __restrict__ Wq,
           const float* __restrict__ Wp, short* __restrict__ frag)
{
    int idx = blockIdx.x * 256 + threadIdx.x;
    if (idx >= FRAG_TOTAL) return;
    float v;
    if (idx < HEADBASE) {
        int T = idx / 3584; int rem = idx - T * 3584;
        int s = rem >> 9;   int e = rem & 511;
        int l = e >> 3, j = e & 7;
        int k = s * 32 + ((l >> 4) << 3) + j;
        int n = ((T & 7) << 4) + (l & 15);
        const float* W = (T < 8) ? Wz : (T < 16) ? Wr : Wh;
        v = (k < KT) ? W[k * HH + n] : 0.f;
    } else {
        int r2 = idx - HEADBASE;
        int ts = r2 >> 9; int e = r2 & 511;
        int t = ts >> 2, s = ts & 3;
        int l = e >> 3, j = e & 7;
        int k = s * 32 + ((l >> 4) << 3) + j;     // < 128
        int c = (t << 4) + (l & 15);
        v = (c < NN) ? Wq[k * NN + c] : (c == NN ? Wp[k] : 0.f);
    }
    frag[idx] = f2bf(v);
}

extern "C" __global__ void __launch_bounds__(1024, 4)
laminar_kernel(const float* __restrict__ packed,
               const float* __restrict__ Wl4,
               const float* __restrict__ Wl23,
               const float* __restrict__ Wsom,
               const float* __restrict__ bz,
               const float* __restrict__ br,
               const float* __restrict__ bh,
               const float* __restrict__ bq,
               const float* __restrict__ bp,
               const short* __restrict__ frag,
               float* __restrict__ out)
{
    const int tid  = threadIdx.x;
    const int r0   = blockIdx.x * RPB;
    const int lane = tid & 63;
    const int w    = tid >> 6;           // 0..15
    const int m    = lane & 15;
    const int q    = lane >> 4;
    // A rows 0..7 = (batch, part): row = batch*2 + part; rows 8..15 duplicate.
    // D rows: lane(q,m): rows q*4+e -> lanes 0-31 give batches 2q (a0+a1),
    // 2q+1 (a2+a3) at col m. In-lane hi/lo combine, no shfl.
    const int arow = m & 7;
    const int ab   = arow >> 1;          // batch row 0..3
    const int ap   = arow & 1;           // 0: hi part, 1: lo part
    const int b0i  = (q & 1) << 1;       // epilogue batch (lanes<32)
    const int b1i  = b0i + 1;

    __shared__ __align__(16) short xa[2][RPB][KP];   // [part][batch][k]: z/r A
    __shared__ __align__(16) short xb[2][RPB][KP];   // hh A: [x, r*h]
    __shared__ __align__(16) short hb[2][RPB][HSTR]; // head A: h_new
    __shared__ float hS[HH][S2];      // h state, [feature][row]
    __shared__ float zgS[HH][S2];     // z gate
    __shared__ float preq[48][S2];    // head pre-acts, [col][row]
    __shared__ __align__(16) float Wl4S[NN * WSTR], Wl23S[NN * WSTR], WsomS[NN * WSTR];
    __shared__ __align__(16) float l4s[RPB][NPAD], l23s[RPB][NPAD];
    __shared__ __align__(16) float soms[RPB][NPAD], adL[RPB][NPAD];
    __shared__ __align__(16) float l4part[RPB][NPAD];   // stim(t)+Wl4*l4(t-1)-adapt(t-1)
    __shared__ __align__(16) float l23dotS[RPB][NPAD];  // Wl23*l23(t-1)
    __shared__ __align__(16) float somdotS[RPB][NPAD];  // Wsom*som(t-1)
    __shared__ float bzL[HH], brL[HH], bhL[HH], bqL[48];
    __shared__ float pvL[RPB];
    __shared__ float bpS;

    // ---- one-time init ----
    for (int i = tid; i < HH; i += 1024) { bzL[i] = bz[i]; brL[i] = br[i]; bhL[i] = bh[i]; }
    for (int i = tid; i < 48; i += 1024) bqL[i] = (i < NN) ? bq[i] : 0.f;
    if (tid == 0) bpS = bp[0];
    for (int idx = tid; idx < NN * NN; idx += 1024) {
        const int i = idx / NN, j = idx - i * NN;
        Wl4S[i * WSTR + j]  = Wl4[idx];
        Wl23S[i * WSTR + j] = Wl23[idx];
        WsomS[i * WSTR + j] = Wsom[idx];
    }
    { short* p = (short*)xa; for (int i = tid; i < 2*RPB*KP; i += 1024) p[i] = 0; }
    { short* p = (short*)xb; for (int i = tid; i < 2*RPB*KP; i += 1024) p[i] = 0; }
    { short* p = (short*)hb; for (int i = tid; i < 2*RPB*HSTR; i += 1024) p[i] = 0; }
    { float* p = (float*)hS; for (int i = tid; i < HH*S2; i += 1024) p[i] = 0.f; }
    { float* p = (float*)l4s; for (int i = tid; i < RPB*NPAD; i += 1024) {
        p[i] = 0.f; ((float*)l23s)[i] = 0.f; ((float*)soms)[i] = 0.f;
        ((float*)adL)[i] = 0.f; ((float*)l23dotS)[i] = 0.f; ((float*)somdotS)[i] = 0.f; } }
    if (tid < RPB) pvL[tid] = 0.f;
    // l4part(0) = stim(0) (all state zero)
    if (tid < RPB * NN) {
        const int r = tid / NN, i = tid - (tid / NN) * NN;
        l4part[r][i] = packed[((size_t)(r0 + r) * TT + 0) * DIN + i];
    }

    // ---- persistent weight fragments (split across wave groups) ----
    bf16x8 FA[7], FB[7];
    if (w < 8) {
        const short* a0 = frag + (w * 7) * 512 + lane * 8;          // Wz tile w
        const short* b0 = frag + ((8 + w) * 7) * 512 + lane * 8;    // Wr tile w
        #pragma unroll
        for (int s = 0; s < 7; ++s) {
            FA[s] = *(const bf16x8*)(a0 + s * 512);
            FB[s] = *(const bf16x8*)(b0 + s * 512);
        }
    } else {
        const int hw8 = w - 8;
        const short* a0 = frag + ((16 + hw8) * 7) * 512 + lane * 8; // Wh tile
        #pragma unroll
        for (int s = 0; s < 7; ++s) FA[s] = *(const bf16x8*)(a0 + s * 512);
        const int hw = (hw8 < 3) ? hw8 : 0;
        const short* b0 = frag + HEADBASE + (hw * 4) * 512 + lane * 8;
        #pragma unroll
        for (int s = 0; s < 4; ++s) FB[s] = *(const bf16x8*)(b0 + s * 512);
        FB[4] = FA[4]; FB[5] = FA[5]; FB[6] = FA[6];   // unused, keep defined
    }

    // ---- aux roles (precomputed; each 144 thr = r in 0..3, i in 0..35) ----
    // P1: l23dot on w8-10
    const int  idA   = (w - 8) * 64 + lane;
    const bool isDotA = (w >= 8 && w < 11) && (idA < 144);
    const int  dvA = isDotA ? idA : 0;
    const int  drA = dvA / 36, diA = dvA - drA * 36;
    const float* dAW = Wl23S + diA * WSTR;
    const float* dAS = &l23s[drA][0];
    float*       dAD = &l23dotS[drA][diA];
    // P1: l4 finalize + l4part base + stim prefetch on w13-15
    const int  idB   = (w - 13) * 64 + lane;
    const bool isL4f = (w >= 13) && (idB < 144);
    const int  lvB = isL4f ? idB : 0;
    const int  lr = lvB / 36, li = lvB - (lvB / 36) * 36;
    // P3: somdot on w0-2
    const int  idC   = w * 64 + lane;
    const bool isDotC = (w < 3) && (idC < 144);
    const int  cvC = isDotC ? idC : 0;
    const int  crC = cvC / 36, ciC = cvC - crC * 36;
    const float* dCW = WsomS + ciC * WSTR;
    const float* dCS = &soms[crC][0];
    float*       dCD = &somdotS[crC][ciC];
    // P5: l4part dot-add on w3-5
    const int  idD   = (w - 3) * 64 + lane;
    const bool isL4p = (w >= 3 && w < 6) && (idD < 144);
    const int  pvD = isL4p ? idD : 0;
    const int  prD = pvD / 36, piD = pvD - prD * 36;
    const float* pW = Wl4S + piD * WSTR;
    const float* pS = &l4s[prD][0];
    float*       pD = &l4part[prD][piD];
    // P5: cue/task staging on w6-7 (4 rows x 19 thr x 2 cols)
    const int  idE   = (w - 6) * 64 + lane;
    const bool isCue = (w >= 6 && w < 8) && (idE < 76);
    const int  evE = isCue ? idE : 0;
    const int  ctr = evE / 19;
    const int  ctc = 36 + 2 * (evE - ctr * 19);   // 36..72 even

    // ---- prologue: cue t=0 staged, t=1 prefetched; stim t=1 prefetched ----
    float ctv0 = 0.f, ctv1 = 0.f, stimreg = 0.f;
    if (isCue) {
        const size_t base0 = ((size_t)(r0 + ctr) * TT + 0) * DIN;
        #pragma unroll
        for (int d = 0; d < 2; ++d) {
            const float v = packed[base0 + ctc + d];
            const short hi = f2bf(v), lo = f2bf(v - bf2f(hi));
            xa[0][ctr][ctc + d] = hi; xa[1][ctr][ctc + d] = lo;
            if (ctc + d >= 64) { xb[0][ctr][ctc + d] = hi; xb[1][ctr][ctc + d] = lo; }
        }
        const size_t base1 = ((size_t)(r0 + ctr) * TT + 1) * DIN;
        ctv0 = packed[base1 + ctc]; ctv1 = packed[base1 + ctc + 1];
    }
    if (isL4f) stimreg = packed[((size_t)(r0 + lr) * TT + 1) * DIN + li];
    __syncthreads();

    for (int t = 0; t < TT; ++t) {
        // ---- P1: z/r gemm (w0-7) || l23dot (w8-10) || l4f+stim (w13-15) ----
        if (w < 8) {
            const short* xaRow = &xa[ap][ab][0];
            bf16x8 Ax[7];
            #pragma unroll
            for (int s = 0; s < 7; ++s)
                Ax[s] = *(const bf16x8*)&xaRow[s * 32 + q * 8];
            f32x4 az = {0.f,0.f,0.f,0.f}, ar = {0.f,0.f,0.f,0.f};
            #pragma unroll
            for (int s = 0; s < 7; ++s) {
                az = MFMA(Ax[s], FA[s], az);
                ar = MFMA(Ax[s], FB[s], ar);
            }
            if (lane < 32) {
                const int f = w * 16 + m;
                const float z0 = az[0] + az[1], z1 = az[2] + az[3];
                const float r0v = ar[0] + ar[1], r1v = ar[2] + ar[3];
                zgS[f][b0i] = sigmf(z0 + bzL[f]);
                zgS[f][b1i] = sigmf(z1 + bzL[f]);
                const float ra = sigmf(r0v + brL[f]) * hS[f][b0i];
                const float rb = sigmf(r1v + brL[f]) * hS[f][b1i];
                const unsigned ph = cvtpk(ra, rb);
                const unsigned pl = cvtpk(ra - lo16f(ph), rb - hi16f(ph));
                xb[0][b0i][DIN + f] = (short)ph;         xb[1][b0i][DIN + f] = (short)pl;
                xb[0][b1i][DIN + f] = (short)(ph >> 16); xb[1][b1i][DIN + f] = (short)(pl >> 16);
            }
        } else if (isDotA) {                   // l23dot from l23(t-1)
            float acc = 0.f;
            #pragma unroll
            for (int j = 0; j < NN; j += 4) {
                const float4 sv = *(const float4*)&dAS[j];
                const float4 wv = *(const float4*)&dAW[j];
                acc += sv.x*wv.x + sv.y*wv.y + sv.z*wv.z + sv.w*wv.w;
            }
            *dAD = acc;
        } else if (isL4f) {                    // l4(t) finalize; l4part(t+1) base
            const float nl4 = 0.9f * l4s[lr][li]
                            + 0.1f * fmaxf(l4part[lr][li] - pvL[lr], 0.f);
            l4s[lr][li] = nl4;
            const float ad = 0.98f * adL[lr][li] + 0.01f * nl4;
            adL[lr][li] = ad;
            l4part[lr][li] = stimreg - ad;     // stim(t+1) - adapt(t)
            const int tn = (t + 2 < TT) ? t + 2 : TT - 1;
            stimreg = packed[((size_t)(r0 + lr) * TT + tn) * DIN + li];
        }
        BAR();

        // ---- P3: h gemm (w8-15) || somdot (w0-2) || PV (w6) ----
        if (w >= 8) {
            const short* xaRow = &xa[ap][ab][0];
            const short* xbRow = &xb[ap][ab][0];
            bf16x8 Op[7];
            Op[0] = *(const bf16x8*)&xaRow[q * 8];
            Op[1] = *(const bf16x8*)&xaRow[32 + q * 8];
            #pragma unroll
            for (int s = 2; s < 7; ++s)
                Op[s] = *(const bf16x8*)&xbRow[s * 32 + q * 8];
            f32x4 a = {0.f,0.f,0.f,0.f}, b = {0.f,0.f,0.f,0.f};
            a = MFMA(Op[0], FA[0], a);
            b = MFMA(Op[1], FA[1], b);
            a = MFMA(Op[2], FA[2], a);
            b = MFMA(Op[3], FA[3], b);
            a = MFMA(Op[4], FA[4], a);
            b = MFMA(Op[5], FA[5], b);
            a = MFMA(Op[6], FA[6], a);
            a = a + b;
            if (lane < 32) {
                const int f = (w - 8) * 16 + m;
                const float s0 = a[0] + a[1], s1 = a[2] + a[3];
                const float hh0 = tanhf_fast(s0 + bhL[f]);
                const float hh1 = tanhf_fast(s1 + bhL[f]);
                const float zg0 = zgS[f][b0i], zg1 = zgS[f][b1i];
                const float hn0 = (1.0f - zg0) * hS[f][b0i] + zg0 * hh0;
                const float hn1 = (1.0f - zg1) * hS[f][b1i] + zg1 * hh1;
                hS[f][b0i] = hn0; hS[f][b1i] = hn1;
                const unsigned ph = cvtpk(hn0, hn1);
                const unsigned pl = cvtpk(hn0 - lo16f(ph), hn1 - hi16f(ph));
                hb[0][b0i][f] = (short)ph;         hb[1][b0i][f] = (short)pl;
                hb[0][b1i][f] = (short)(ph >> 16); hb[1][b1i][f] = (short)(pl >> 16);
                xa[0][b0i][DIN + f] = (short)ph;         xa[1][b0i][DIN + f] = (short)pl;
                xa[0][b1i][DIN + f] = (short)(ph >> 16); xa[1][b1i][DIN + f] = (short)(pl >> 16);
            }
        } else if (isDotC) {                   // somdot from som(t-1)
            float acc = 0.f;
            #pragma unroll
            for (int j = 0; j < NN; j += 4) {
                const float4 sv = *(const float4*)&dCS[j];
                const float4 wv = *(const float4*)&dCW[j];
                acc += sv.x*wv.x + sv.y*wv.y + sv.z*wv.z + sv.w*wv.w;
            }
            *dCD = acc;
        } else if (w == 6) {                   // PV: l4(t) + l23(t-1), DPP reduce
            const int row = q;                 // 0..3
            float s = l4s[row][m] + l23s[row][m] + l4s[row][m + 16] + l23s[row][m + 16];
            if (m < 4) s += l4s[row][m + 32] + l23s[row][m + 32];
            s = red16_sum(s);
            if (m == 0) pvL[row] = 0.9f * pvL[row] + 0.1f * fmaxf(s * (1.0f / 36.0f), 0.f);
        }
        BAR();

        // ---- P5: heads (w8-10) || l4part-add (w3-5) || cue (w6-7) ----
        if (w >= 8 && w < 11) {
            const short* hbRow = &hb[ap][ab][0];
            bf16x8 Hk[4];
            #pragma unroll
            for (int s = 0; s < 4; ++s)
                Hk[s] = *(const bf16x8*)&hbRow[s * 32 + q * 8];
            f32x4 a = {0.f,0.f,0.f,0.f};
            #pragma unroll
            for (int s = 0; s < 4; ++s) a = MFMA(Hk[s], FB[s], a);
            if (lane < 32) {
                const int c = (w - 8) * 16 + m;
                preq[c][b0i] = a[0] + a[1];
                preq[c][b1i] = a[2] + a[3];
            }
        } else if (isL4p) {                    // l4part(t+1) += Wl4*l4(t)
            float acc = *pD;
            #pragma unroll
            for (int j = 0; j < NN; j += 4) {
                const float4 sv = *(const float4*)&pS[j];
                const float4 wv = *(const float4*)&pW[j];
                acc += sv.x*wv.x + sv.y*wv.y + sv.z*wv.z + sv.w*wv.w;
            }
            *pD = acc;
        } else if (isCue) {                    // cue/task(t+1) -> LDS; prefetch t+2
            const unsigned ph = cvtpk(ctv0, ctv1);
            const unsigned pl = cvtpk(ctv0 - lo16f(ph), ctv1 - hi16f(ph));
            xa[0][ctr][ctc]     = (short)ph;         xa[1][ctr][ctc]     = (short)pl;
            xa[0][ctr][ctc + 1] = (short)(ph >> 16); xa[1][ctr][ctc + 1] = (short)(pl >> 16);
            if (ctc >= 64) {   // ctc even, so ctc>=64 <=> ctc+1>=64
                xb[0][ctr][ctc]     = (short)ph;         xb[1][ctr][ctc]     = (short)pl;
                xb[0][ctr][ctc + 1] = (short)(ph >> 16); xb[1][ctr][ctc + 1] = (short)(pl >> 16);
            }
            const int tn = (t + 2 < TT) ? t + 2 : TT - 1;
            const size_t base = ((size_t)(r0 + ctr) * TT + tn) * DIN;
            ctv0 = packed[base + ctc]; ctv1 = packed[base + ctc + 1];
        }
        BAR();

        // ---- P6: softmax+pi (DPP butterfly) + pointwise SOM/L23 + output ----
        if (w < 4) {
            const int rr = w;   // 0..3
            const float v0 = preq[m][rr] + bqL[m];
            const float v1 = preq[m + 16][rr] + bqL[m + 16];
            const float v2 = (m < 4) ? (preq[m + 32][rr] + bqL[m + 32]) : -1e30f;
            const float pi = sigmf(preq[36][rr] + bpS);
            const float mx = red16_max(fmaxf(fmaxf(v0, v1), v2));
            const float e0 = __expf(v0 - mx);
            const float e1 = __expf(v1 - mx);
            const float e2 = (m < 4) ? __expf(v2 - mx) : 0.f;
            const float ss = red16_sum(e0 + e1 + e2);
            const float sc = fastrcp(ss) * pi;
            if (lane < 16) {
                const float pv = pvL[rr];
                const size_t outb = ((size_t)(r0 + rr) * TT + t) * NN;
                float ln01[2];
                #pragma unroll
                for (int t2 = 0; t2 < 2; ++t2) {
                    const int i = m + 16 * t2;
                    const float dt = (t2 ? e1 : e0) * sc;
                    const float sn = 0.9f * soms[rr][i]
                                   + 0.1f * fmaxf(dt + somdotS[rr][i], 0.f);
                    soms[rr][i] = sn;
                    const float acc2 = (l4s[rr][i] - dt) * (1.0f + 0.5f * dt)
                                     + l23dotS[rr][i] - 0.8f * sn - pv;
                    const float ln = 0.9f * l23s[rr][i] + 0.1f * fmaxf(acc2, 0.f);
                    l23s[rr][i] = ln;
                    out[outb + i] = ln;
                    ln01[t2] = ln;
                }
                const unsigned ph = cvtpk(ln01[0], ln01[1]);
                const unsigned pl = cvtpk(ln01[0] - lo16f(ph), ln01[1] - hi16f(ph));
                xa[0][rr][m]      = (short)ph;         xa[1][rr][m]      = (short)pl;
                xa[0][rr][m + 16] = (short)(ph >> 16); xa[1][rr][m + 16] = (short)(pl >> 16);
                if (m < 4) {
                    const int i = m + 32;
                    const float dt = e2 * sc;
                    const float sn = 0.9f * soms[rr][i]
                                   + 0.1f * fmaxf(dt + somdotS[rr][i], 0.f);
                    soms[rr][i] = sn;
                    const float acc2 = (l4s[rr][i] - dt) * (1.0f + 0.5f * dt)
                                     + l23dotS[rr][i] - 0.8f * sn - pv;
                    const float ln = 0.9f * l23s[rr][i] + 0.1f * fmaxf(acc2, 0.f);
                    l23s[rr][i] = ln;
                    out[outb + i] = ln;
                    const short hi2 = f2bf(ln);
                    xa[0][rr][i] = hi2; xa[1][rr][i] = f2bf(ln - bf2f(hi2));
                }
            }
        }
        BAR();
    }
}

extern "C" void kernel_launch(void* const* d_in, const int* in_sizes, int n_in,
                              void* d_out, int out_size, void* d_ws, size_t ws_size,
                              hipStream_t stream) {
    (void)in_sizes; (void)n_in; (void)out_size; (void)ws_size;
    const float* packed = (const float*)d_in[0];
    const float* Wl4    = (const float*)d_in[1];
    const float* Wl23   = (const float*)d_in[2];
    const float* Wsom   = (const float*)d_in[3];
    const float* Wz     = (const float*)d_in[4];
    const float* Wr     = (const float*)d_in[5];
    const float* Wh     = (const float*)d_in[6];
    const float* bz     = (const float*)d_in[7];
    const float* br     = (const float*)d_in[8];
    const float* bh     = (const float*)d_in[9];
    const float* Wq     = (const float*)d_in[10];
    const float* bq     = (const float*)d_in[11];
    const float* Wp     = (const float*)d_in[12];
    const float* bp     = (const float*)d_in[13];
    float* out  = (float*)d_out;
    short* frag = (short*)d_ws;   // needs 184320 B

    init_frags<<<(FRAG_TOTAL + 255) / 256, 256, 0, stream>>>(Wz, Wr, Wh, Wq, Wp, frag);
    laminar_kernel<<<256, 1024, 0, stream>>>(packed, Wl4, Wl23, Wsom,
                                             bz, br, bh, bq, bp, frag, out);
}